// Round 4
// baseline (304.029 us; speedup 1.0000x reference)
//
#include <hip/hip_runtime.h>
#include <math.h>

#define NUM_HEADS   16
#define HEAD_DIM    64
#define KMAXN       64
#define LOCAL_WIN   512
#define LOG_N       17
#define LEAF_START  131072
#define MAX_LEN_TOK 65536
#define ROW         1024      // NUM_HEADS*HEAD_DIM floats per token
#define SLICE       65536     // 64 tokens * ROW floats per partial slice
#define MAXN        34

typedef float vf4 __attribute__((ext_vector_type(4)));

__device__ __forceinline__ vf4 ntload(const float* p) {
    return __builtin_nontemporal_load((const vf4*)p);
}

struct K1Args {
    int nNodes;       // big (C>1) nodes only
    int a[MAXN];      // start token
    int cpb[MAXN];    // chunks per block
    int C[MAXN];      // total chunks
    int CB[MAXN];     // chunk-blocks
    int K[MAXN];      // kept tokens per node (<=64)
    int off[MAXN];    // partial buffer offset (floats)
    int bbase[MAXN];  // first blockIdx for this node
};

struct K2Args {
    int nNodes;       // ALL cover-set nodes
    int nTilesTotal;  // 16*(nNodes+1) incl. local blocks
    int doCombine;    // 1 if k1 zeroed the counter (nBig>0)
    int K[MAXN];
    int C[MAXN];
    int CB[MAXN];
    int off[MAXN];
    int a[MAXN];
    int depth[MAXN];
};

// ---------------- K1: strided chunk-sum partials, streaming shape.
// Only C>1 nodes. Block = (node, cb, kg), cb-MAJOR: co-resident blocks read
// adjacent memory. Each block owns 4 adjacent k-rows -> per chunk one 16 KB
// contiguous burst; 2-chunk unroll = 8 independent nt-loads in flight.
// Host balances CB so total grid = 768 = exactly 3 blocks/CU (no 4th-block
// tail). 1/C applied in the fused K2. Block 0 zeroes the combine counter.
__global__ __launch_bounds__(256, 4) void k1_reduce(const float* __restrict__ v,
                                                    float* __restrict__ ws,
                                                    unsigned* __restrict__ cnt,
                                                    K1Args A) {
    int b = blockIdx.x;
    if (b == 0 && threadIdx.x == 0) *cnt = 0u;   // stream order -> visible to k2
    int node = 0;
    for (int i = 1; i < A.nNodes; ++i)
        if (b >= A.bbase[i]) node = i;     // uniform scalar scan
    int lb  = b - A.bbase[node];
    int K   = A.K[node];
    int kgc = (K + 3) >> 2;
    int cb  = lb / kgc;                    // cb-major
    int kg  = lb - cb * kgc;
    int k0  = kg * 4;
    int RK  = K - k0; if (RK > 4) RK = 4;
    int c0  = cb * A.cpb[node];
    int c1  = c0 + A.cpb[node];
    int C   = A.C[node];
    if (c1 > C) c1 = C;

    int j4 = threadIdx.x * 4;              // float offset of this thread's float4

    vf4 acc0 = 0.f, acc1 = 0.f, acc2 = 0.f, acc3 = 0.f;

    if (RK == 4) {
        int c = c0;
        for (; c + 2 <= c1; c += 2) {
            const float* p0 = v + (long)(A.a[node] + c * 64 + k0) * ROW + j4;
            const float* p1 = p0 + SLICE;
            vf4 y0 = ntload(p0);
            vf4 y1 = ntload(p0 + ROW);
            vf4 y2 = ntload(p0 + 2 * ROW);
            vf4 y3 = ntload(p0 + 3 * ROW);
            vf4 z0 = ntload(p1);
            vf4 z1 = ntload(p1 + ROW);
            vf4 z2 = ntload(p1 + 2 * ROW);
            vf4 z3 = ntload(p1 + 3 * ROW);
            acc0 += y0 + z0; acc1 += y1 + z1; acc2 += y2 + z2; acc3 += y3 + z3;
        }
        if (c < c1) {
            const float* p0 = v + (long)(A.a[node] + c * 64 + k0) * ROW + j4;
            acc0 += ntload(p0);
            acc1 += ntload(p0 + ROW);
            acc2 += ntload(p0 + 2 * ROW);
            acc3 += ntload(p0 + 3 * ROW);
        }
    } else {
        for (int c = c0; c < c1; ++c) {
            const float* p0 = v + (long)(A.a[node] + c * 64 + k0) * ROW + j4;
            if (RK > 0) acc0 += ntload(p0);
            if (RK > 1) acc1 += ntload(p0 + ROW);
            if (RK > 2) acc2 += ntload(p0 + 2 * ROW);
            if (RK > 3) acc3 += ntload(p0 + 3 * ROW);
        }
    }

    float* wp = ws + (long)A.off[node] + (long)cb * SLICE + (long)k0 * ROW + j4;
    if (RK > 0) *(vf4*)(wp)           = acc0;
    if (RK > 1) *(vf4*)(wp + ROW)     = acc1;
    if (RK > 2) *(vf4*)(wp + 2 * ROW) = acc2;
    if (RK > 3) *(vf4*)(wp + 3 * ROW) = acc3;
}

// ---------------- K2 fused: per-(node,head) blocks finalize the CB-reduction
// for THEIR head slice (the 16 head blocks of a node partition ROW, so the
// partial slices are read exactly once in aggregate), then do the node
// attention from LDS. blockIdx.y == nNodes blocks do the local-window
// attention concurrently. Last finishing block (device-scope counter, zeroed
// by k1) writes the final combined output — no separate combine launch.
__global__ __launch_bounds__(512) void k2_fused(const float* __restrict__ v,
                                                const float* __restrict__ ws,
                                                const float* __restrict__ q,
                                                const float* __restrict__ W,
                                                const float* __restrict__ temp,
                                                float* __restrict__ node_out,
                                                float* __restrict__ local_out,
                                                float* __restrict__ out,
                                                unsigned* __restrict__ cnt,
                                                int pos, K2Args A) {
    int h    = blockIdx.x;
    int node = blockIdx.y;
    int tid  = threadIdx.x;
    int lane = tid & 63;
    int w    = tid >> 6;                   // wave 0..7

    __shared__ float fh[64][64];           // node path: f[h] slice, [k][d]
    __shared__ float qs[64], qds[64], sv[64], ps[64];
    __shared__ float red[8][64];
    __shared__ float sc[LOCAL_WIN];        // local path
    __shared__ float wred[16];
    __shared__ float mS[2];
    __shared__ unsigned lastf;

    if (node < A.nNodes) {
        // -------- tree-node attention --------
        int K = A.K[node];
        if (tid < 64) qs[tid] = q[h * 64 + tid];

        const float* bp; int CB; float invC;
        if (A.C[node] > 1) {
            bp   = ws + (long)A.off[node] + h * 64;
            CB   = A.CB[node];
            invC = 1.0f / (float)A.C[node];
        } else {
            bp   = v + (long)A.a[node] * ROW + h * 64;   // read chunk directly
            CB   = 1;
            invC = 1.0f;
        }
        // 64 rows x 16 float4-cols = 1024 (r,c4) pairs; 2 per thread.
        for (int id = tid; id < 1024; id += 512) {
            int r  = id >> 4;
            int c4 = (id & 15) << 2;
            if (r < K) {
                vf4 s0 = 0.f, s1 = 0.f, s2 = 0.f, s3 = 0.f;
                const float* p = bp + (long)r * ROW + c4;
                int cb = 0;
                for (; cb + 4 <= CB; cb += 4) {
                    s0 += *(const vf4*)(p + (long)cb * SLICE);
                    s1 += *(const vf4*)(p + (long)(cb + 1) * SLICE);
                    s2 += *(const vf4*)(p + (long)(cb + 2) * SLICE);
                    s3 += *(const vf4*)(p + (long)(cb + 3) * SLICE);
                }
                for (; cb < CB; ++cb) s0 += *(const vf4*)(p + (long)cb * SLICE);
                s0 += s1; s2 += s3; s0 += s2;
                s0 *= invC;
                *(vf4*)&fh[r][c4] = s0;
            }
        }
        __syncthreads();

        // q_depth = q + q @ W[dep]^T ; 8 waves x 8 elems each
        int dep = A.depth[node];
        float qp = 0.f;
        const float* Wr = W + ((long)dep * 64 + lane) * 64;
        #pragma unroll
        for (int e = w * 8; e < w * 8 + 8; ++e) qp += qs[e] * Wr[e];
        red[w][lane] = qp;
        __syncthreads();
        if (w == 0) {
            float t = qs[lane];
            #pragma unroll
            for (int i = 0; i < 8; ++i) t += red[i][lane];
            qds[lane] = t;
        }
        __syncthreads();
        float qd    = qds[lane];
        float sp    = log1pf(expf(temp[dep]));
        float scale = 1.0f / ((sp + 1e-6f) * 8.0f);

        for (int k = w; k < K; k += 8) {
            float p = qd * fh[k][lane];
            #pragma unroll
            for (int m = 1; m < 64; m <<= 1) p += __shfl_xor(p, m, 64);
            if (lane == 0) sv[k] = p * scale;
        }
        __syncthreads();

        if (w == 0) {
            float s  = (lane < K) ? sv[lane] : -1e30f;
            float mx = s;
            #pragma unroll
            for (int m = 1; m < 64; m <<= 1) mx = fmaxf(mx, __shfl_xor(mx, m, 64));
            float e = (lane < K) ? expf(s - mx) : 0.f;
            float S = e;
            #pragma unroll
            for (int m = 1; m < 64; m <<= 1) S += __shfl_xor(S, m, 64);
            ps[lane] = e / S;
        }
        __syncthreads();

        float o = 0.f;
        for (int k = w; k < K; k += 8) o += ps[k] * fh[k][lane];
        red[w][lane] = o;
        __syncthreads();
        if (w == 0) {
            float t = 0.f;
            #pragma unroll
            for (int i = 0; i < 8; ++i) t += red[i][lane];
            node_out[node * ROW + h * 64 + lane] = t;
        }
    } else {
        // -------- local-window attention (writes local_out) ----
        int nloc = pos < LOCAL_WIN ? pos : LOCAL_WIN;
        int t0   = pos - nloc;

        if (tid < 64) qs[tid] = q[h * 64 + tid];
        __syncthreads();

        // phase A: one token per thread; serial dot over d
        float s = -1e30f;
        if (tid < nloc) {
            const float* vr = v + (long)(t0 + tid) * ROW + h * 64;
            float acc = 0.f;
            #pragma unroll 8
            for (int d = 0; d < 64; ++d) acc += qs[d] * vr[d];
            s = acc * 0.125f;
        }
        float mx = s;
        #pragma unroll
        for (int m = 1; m < 64; m <<= 1) mx = fmaxf(mx, __shfl_xor(mx, m, 64));
        if (lane == 0) wred[w] = mx;
        __syncthreads();
        if (tid == 0) {
            float m2 = wred[0];
            for (int i = 1; i < 8; ++i) m2 = fmaxf(m2, wred[i]);
            mS[0] = m2;
        }
        __syncthreads();
        float m = mS[0];

        float e = (tid < nloc) ? expf(s - m) : 0.f;
        sc[tid] = e;
        float su = e;
        #pragma unroll
        for (int mm = 1; mm < 64; mm <<= 1) su += __shfl_xor(su, mm, 64);
        if (lane == 0) wred[8 + w] = su;
        __syncthreads();
        if (tid == 0) {
            float S2 = 0.f;
            for (int i = 0; i < 8; ++i) S2 += wred[8 + i];
            mS[1] = S2;
        }
        __syncthreads();
        float S = mS[1];

        // phase B: lane = d, wave w handles tokens [w*64, w*64+64)
        float acc = 0.f;
        {
            const float* vb = v + (long)t0 * ROW + h * 64 + lane;
            int tb = w * 64;
            #pragma unroll 4
            for (int i = 0; i < 64; ++i) {
                int t = tb + i;
                if (t < nloc) acc += sc[t] * vb[(long)t * ROW];
            }
        }
        red[w][lane] = acc;
        __syncthreads();

        if (w == 0) {
            float tot = 0.f;
            #pragma unroll
            for (int i = 0; i < 8; ++i) tot += red[i][lane];
            local_out[h * 64 + lane] = (nloc > 0) ? tot / S : 0.f;
        }
    }

    // -------- last-block combine (release/acquire via device-scope atomic) --
    __threadfence();                       // release: writers' stores visible
    __syncthreads();                       // tid0's atomic after all fences
    if (tid == 0) {
        unsigned ok = 0u;
        if (A.doCombine) {
            unsigned old = atomicAdd(cnt, 1u);
            ok = (old == (unsigned)(A.nTilesTotal - 1)) ? 1u : 0u;
        }
        lastf = ok;
    }
    __syncthreads();
    if (lastf) {
        __threadfence();                   // acquire side
        float invN = 1.0f / (float)A.nNodes;
        for (int i = tid; i < ROW; i += 512) {
            float tr = 0.f;
            for (int n = 0; n < A.nNodes; ++n) tr += node_out[(long)n * ROW + i];
            out[i] = local_out[i] + tr * invN;
        }
    }
}

// Fallback combine (only when nBig==0, e.g. tiny pos — counter not zeroed)
__global__ __launch_bounds__(256) void k3_combine(const float* __restrict__ node_out,
                                                  const float* __restrict__ local_out,
                                                  int nNodes,
                                                  float* __restrict__ out) {
    int i = blockIdx.x * 256 + threadIdx.x;
    float tr = 0.f;
    for (int n = 0; n < nNodes; ++n) tr += node_out[(long)n * ROW + i];
    if (nNodes > 0) tr /= (float)nNodes;
    out[i] = local_out[i] + tr;
}

static int floor_log2_host(unsigned x) { int r = 0; while (x >>= 1) ++r; return r; }

extern "C" void kernel_launch(void* const* d_in, const int* in_sizes, int n_in,
                              void* d_out, int out_size, void* d_ws, size_t ws_size,
                              hipStream_t stream) {
    const float* v    = (const float*)d_in[0];
    const float* q    = (const float*)d_in[1];
    const float* W    = (const float*)d_in[2];
    const float* temp = (const float*)d_in[3];
    float* out        = (float*)d_out;
    float* ws         = (float*)d_ws;

    int pos = in_sizes[0] / ROW;

    int n_nodes = 0;
    int nv[MAXN], nd[MAXN];
    if (pos > 0) {
        long l = LEAF_START;
        long r = LEAF_START + (pos < MAX_LEN_TOK ? pos : MAX_LEN_TOK);
        while (l < r) {
            if (l & 1) { nv[n_nodes] = (int)l; nd[n_nodes] = LOG_N - floor_log2_host((unsigned)l); ++n_nodes; ++l; }
            if (r & 1) { --r; nv[n_nodes] = (int)r; nd[n_nodes] = LOG_N - floor_log2_host((unsigned)r); ++n_nodes; }
            l >>= 1; r >>= 1;
        }
    }

    // ---- collect big (C>1) nodes; balance CB so the k1 grid = 16*TGT blocks,
    //      i.e. TGT=48 -> 768 blocks = exactly 3/CU on 256 CUs (no tail).
    int bigIdx[MAXN], bigC[MAXN], bigCB[MAXN], bigCpb[MAXN];
    int nBig = 0; long totC = 0;
    for (int i = 0; i < n_nodes; ++i) {
        int L = 1 << nd[i];
        int C = (L > KMAXN) ? L / KMAXN : 1;
        if (C > 1) { bigIdx[nBig] = i; bigC[nBig] = C; totC += C; ++nBig; }
    }
    long wsFloats = (long)(ws_size / 4);
    int TGT = 48;
    if (nBig > 0) {
        for (;;) {
            long sum = 0;
            for (int j = 0; j < nBig; ++j) {
                int cb = (int)((long)bigC[j] * TGT / totC);
                if (cb < 1) cb = 1;
                if (cb > bigC[j]) cb = bigC[j];
                bigCB[j] = cb; sum += cb;
            }
            // bump toward TGT on nodes with most chunks per block
            while (sum < TGT) {
                int best = -1; double br = 0.0;
                for (int j = 0; j < nBig; ++j)
                    if (bigCB[j] < bigC[j]) {
                        double r2 = (double)bigC[j] / bigCB[j];
                        if (r2 > br) { br = r2; best = j; }
                    }
                if (best < 0) break;
                ++bigCB[best]; ++sum;
            }
            // finalize cpb and recompute CB (no empty blocks)
            long slices = 0;
            for (int j = 0; j < nBig; ++j) {
                bigCpb[j] = (bigC[j] + bigCB[j] - 1) / bigCB[j];
                bigCB[j]  = (bigC[j] + bigCpb[j] - 1) / bigCpb[j];
                slices += bigCB[j];
            }
            long need = slices * (long)SLICE + (long)n_nodes * ROW + ROW + 64;
            if (need <= wsFloats || TGT <= 8) break;
            TGT >>= 1;
        }
    }

    K1Args A1{}; K2Args A2{};
    A2.nNodes = n_nodes;
    A2.nTilesTotal = NUM_HEADS * (n_nodes + 1);
    A2.doCombine = (nBig > 0) ? 1 : 0;
    int off = 0, bb = 0;
    for (int i = 0; i < n_nodes; ++i) {
        int depth = nd[i];
        int L = 1 << depth;
        int a = (nv[i] << depth) - LEAF_START;
        int K = (L < KMAXN) ? L : KMAXN;
        int C = (L > KMAXN) ? L / KMAXN : 1;
        A2.K[i] = K; A2.C[i] = C; A2.a[i] = a; A2.depth[i] = depth;
        A2.CB[i] = 1; A2.off[i] = 0;
    }
    for (int j = 0; j < nBig; ++j) {
        int i = bigIdx[j];
        int K = KMAXN;                    // C>1 => L>=128 => K=64
        A1.a[j] = A2.a[i]; A1.cpb[j] = bigCpb[j]; A1.C[j] = bigC[j];
        A1.CB[j] = bigCB[j]; A1.K[j] = K;
        A1.off[j] = off; A1.bbase[j] = bb;
        A2.CB[i] = bigCB[j]; A2.off[i] = off;
        off += bigCB[j] * SLICE;
        bb  += ((K + 3) / 4) * bigCB[j];  // 16 k-groups per cb, cb-major
    }
    A1.nNodes = nBig;

    float* node_outp  = ws + (long)off;                    // n_nodes * ROW
    float* local_outp = node_outp + (long)n_nodes * ROW;   // ROW
    unsigned* cntp    = (unsigned*)(local_outp + ROW);     // combine counter

    if (nBig > 0)
        hipLaunchKernelGGL(k1_reduce, dim3(bb), dim3(256), 0, stream, v, ws, cntp, A1);
    hipLaunchKernelGGL(k2_fused, dim3(NUM_HEADS, n_nodes + 1), dim3(512), 0, stream,
                       v, ws, q, W, temp, node_outp, local_outp, out, cntp, pos, A2);
    if (nBig == 0)
        hipLaunchKernelGGL(k3_combine, dim3(4), dim3(256), 0, stream,
                           node_outp, local_outp, n_nodes, out);
}

// Round 5
// 288.248 us; speedup vs baseline: 1.0547x; 1.0547x over previous
//
#include <hip/hip_runtime.h>
#include <math.h>

#define NUM_HEADS   16
#define HEAD_DIM    64
#define KMAXN       64
#define LOCAL_WIN   512
#define LOG_N       17
#define LEAF_START  131072
#define MAX_LEN_TOK 65536
#define ROW         1024      // NUM_HEADS*HEAD_DIM floats per token
#define SLICE       65536     // 64 tokens * ROW floats per partial slice
#define MAXN        34

typedef float vf4 __attribute__((ext_vector_type(4)));

__device__ __forceinline__ vf4 ntload(const float* p) {
    return __builtin_nontemporal_load((const vf4*)p);
}

struct K1Args {
    int nNodes;       // big (C>1) nodes only
    int a[MAXN];      // start token
    int cpb[MAXN];    // chunks per block
    int C[MAXN];      // total chunks
    int CB[MAXN];     // chunk-blocks
    int off[MAXN];    // partial buffer offset (floats)
    int bbase[MAXN];  // first blockIdx for this node
};

struct K2Args {
    int nNodes;       // ALL cover-set nodes
    int K[MAXN];
    int C[MAXN];
    int CB[MAXN];
    int off[MAXN];
    int a[MAXN];
    int depth[MAXN];
};

// ---------------- K1: strided chunk-sum partials, streaming shape.
// Only C>1 nodes (K=64 always). Block = (node, cb, kg) with cb-MAJOR ordering:
// co-resident blocks read adjacent memory. Each block owns 2 adjacent k-rows
// (32 kg per cb) -> per chunk one 8 KB contiguous burst; 4-chunk unroll keeps
// 8 independent nt-loads in flight per thread (same as the verified 4-row/
// 2-chunk shape). cpb=32 halves the partial-slice count vs round 1 at the
// same ~830-block grid. 1/C applied in the fused K2.
__global__ __launch_bounds__(256, 4) void k1_reduce(const float* __restrict__ v,
                                                    float* __restrict__ ws,
                                                    K1Args A) {
    int b = blockIdx.x;
    int node = 0;
    for (int i = 1; i < A.nNodes; ++i)
        if (b >= A.bbase[i]) node = i;     // uniform scalar scan
    int lb  = b - A.bbase[node];
    int cb  = lb >> 5;                     // cb-major, 32 k-groups per cb
    int kg  = lb & 31;
    int k0  = kg * 2;                      // 2 rows per group
    int c0  = cb * A.cpb[node];
    int c1  = c0 + A.cpb[node];
    int C   = A.C[node];
    if (c1 > C) c1 = C;
    int a   = A.a[node];

    int j4 = threadIdx.x * 4;              // float offset of this thread's float4

    vf4 acc0 = 0.f, acc1 = 0.f;

    int c = c0;
    for (; c + 4 <= c1; c += 4) {
        const float* p0 = v + (long)(a + c * 64 + k0) * ROW + j4;
        vf4 y0 = ntload(p0);
        vf4 y1 = ntload(p0 + ROW);
        vf4 y2 = ntload(p0 + SLICE);
        vf4 y3 = ntload(p0 + SLICE + ROW);
        vf4 y4 = ntload(p0 + 2 * SLICE);
        vf4 y5 = ntload(p0 + 2 * SLICE + ROW);
        vf4 y6 = ntload(p0 + 3 * SLICE);
        vf4 y7 = ntload(p0 + 3 * SLICE + ROW);
        acc0 += y0 + y2 + y4 + y6;
        acc1 += y1 + y3 + y5 + y7;
    }
    for (; c < c1; ++c) {
        const float* p0 = v + (long)(a + c * 64 + k0) * ROW + j4;
        acc0 += ntload(p0);
        acc1 += ntload(p0 + ROW);
    }

    float* wp = ws + (long)A.off[node] + (long)cb * SLICE + (long)k0 * ROW + j4;
    *(vf4*)(wp)       = acc0;
    *(vf4*)(wp + ROW) = acc1;
}

// ---------------- K2 fused: per-(node,head) blocks finalize the CB-reduction
// for THEIR head slice (the 16 head blocks of a node partition ROW, so the
// partial slices are read exactly once in aggregate), then do the node
// attention from LDS. blockIdx.y == 0 blocks do the local-window attention
// (dispatched FIRST, since they're the longest); nodes are y-1.
__global__ __launch_bounds__(512) void k2_fused(const float* __restrict__ v,
                                                const float* __restrict__ ws,
                                                const float* __restrict__ q,
                                                const float* __restrict__ W,
                                                const float* __restrict__ temp,
                                                float* __restrict__ node_out,
                                                float* __restrict__ local_out,
                                                int pos, K2Args A) {
    int h    = blockIdx.x;
    int node = (int)blockIdx.y - 1;        // y==0 -> local path
    int tid  = threadIdx.x;
    int lane = tid & 63;
    int w    = tid >> 6;                   // wave 0..7

    __shared__ float fh[64][64];           // node path: f[h] slice, [k][d]
    __shared__ float qs[64], qds[64], sv[64], ps[64];
    __shared__ float red[8][64];
    __shared__ float sc[LOCAL_WIN];        // local path
    __shared__ float wred[16];
    __shared__ float mS[2];

    if (node >= 0) {
        // -------- tree-node attention --------
        int K = A.K[node];
        if (tid < 64) qs[tid] = q[h * 64 + tid];

        const float* bp; int CB; float invC;
        if (A.C[node] > 1) {
            bp   = ws + (long)A.off[node] + h * 64;
            CB   = A.CB[node];
            invC = 1.0f / (float)A.C[node];
        } else {
            bp   = v + (long)A.a[node] * ROW + h * 64;   // read chunk directly
            CB   = 1;
            invC = 1.0f;
        }
        // 64 rows x 16 float4-cols = 1024 (r,c4) pairs; 2 per thread.
        for (int id = tid; id < 1024; id += 512) {
            int r  = id >> 4;
            int c4 = (id & 15) << 2;
            if (r < K) {
                vf4 s0 = 0.f, s1 = 0.f, s2 = 0.f, s3 = 0.f;
                const float* p = bp + (long)r * ROW + c4;
                int cb = 0;
                for (; cb + 4 <= CB; cb += 4) {
                    s0 += *(const vf4*)(p + (long)cb * SLICE);
                    s1 += *(const vf4*)(p + (long)(cb + 1) * SLICE);
                    s2 += *(const vf4*)(p + (long)(cb + 2) * SLICE);
                    s3 += *(const vf4*)(p + (long)(cb + 3) * SLICE);
                }
                for (; cb < CB; ++cb) s0 += *(const vf4*)(p + (long)cb * SLICE);
                s0 += s1; s2 += s3; s0 += s2;
                s0 *= invC;
                *(vf4*)&fh[r][c4] = s0;
            }
        }
        __syncthreads();

        // q_depth = q + q @ W[dep]^T ; 8 waves x 8 elems each
        int dep = A.depth[node];
        float qp = 0.f;
        const float* Wr = W + ((long)dep * 64 + lane) * 64;
        #pragma unroll
        for (int e = w * 8; e < w * 8 + 8; ++e) qp += qs[e] * Wr[e];
        red[w][lane] = qp;
        __syncthreads();
        if (w == 0) {
            float t = qs[lane];
            #pragma unroll
            for (int i = 0; i < 8; ++i) t += red[i][lane];
            qds[lane] = t;
        }
        __syncthreads();
        float qd    = qds[lane];
        float sp    = log1pf(expf(temp[dep]));
        float scale = 1.0f / ((sp + 1e-6f) * 8.0f);

        for (int k = w; k < K; k += 8) {
            float p = qd * fh[k][lane];
            #pragma unroll
            for (int m = 1; m < 64; m <<= 1) p += __shfl_xor(p, m, 64);
            if (lane == 0) sv[k] = p * scale;
        }
        __syncthreads();

        if (w == 0) {
            float s  = (lane < K) ? sv[lane] : -1e30f;
            float mx = s;
            #pragma unroll
            for (int m = 1; m < 64; m <<= 1) mx = fmaxf(mx, __shfl_xor(mx, m, 64));
            float e = (lane < K) ? expf(s - mx) : 0.f;
            float S = e;
            #pragma unroll
            for (int m = 1; m < 64; m <<= 1) S += __shfl_xor(S, m, 64);
            ps[lane] = e / S;
        }
        __syncthreads();

        float o = 0.f;
        for (int k = w; k < K; k += 8) o += ps[k] * fh[k][lane];
        red[w][lane] = o;
        __syncthreads();
        if (w == 0) {
            float t = 0.f;
            #pragma unroll
            for (int i = 0; i < 8; ++i) t += red[i][lane];
            node_out[node * ROW + h * 64 + lane] = t;
        }
    } else {
        // -------- local-window attention (writes local_out, no combine) ----
        int nloc = pos < LOCAL_WIN ? pos : LOCAL_WIN;
        int t0   = pos - nloc;

        if (tid < 64) qs[tid] = q[h * 64 + tid];
        __syncthreads();

        // phase A: one token per thread; serial dot over d
        float s = -1e30f;
        if (tid < nloc) {
            const float* vr = v + (long)(t0 + tid) * ROW + h * 64;
            float acc = 0.f;
            #pragma unroll 8
            for (int d = 0; d < 64; ++d) acc += qs[d] * vr[d];
            s = acc * 0.125f;
        }
        float mx = s;
        #pragma unroll
        for (int m = 1; m < 64; m <<= 1) mx = fmaxf(mx, __shfl_xor(mx, m, 64));
        if (lane == 0) wred[w] = mx;
        __syncthreads();
        if (tid == 0) {
            float m2 = wred[0];
            for (int i = 1; i < 8; ++i) m2 = fmaxf(m2, wred[i]);
            mS[0] = m2;
        }
        __syncthreads();
        float m = mS[0];

        float e = (tid < nloc) ? expf(s - m) : 0.f;
        sc[tid] = e;
        float su = e;
        #pragma unroll
        for (int mm = 1; mm < 64; mm <<= 1) su += __shfl_xor(su, mm, 64);
        if (lane == 0) wred[8 + w] = su;
        __syncthreads();
        if (tid == 0) {
            float S2 = 0.f;
            for (int i = 0; i < 8; ++i) S2 += wred[8 + i];
            mS[1] = S2;
        }
        __syncthreads();
        float S = mS[1];

        // phase B: lane = d, wave w handles tokens [w*64, w*64+64)
        float acc = 0.f;
        {
            const float* vb = v + (long)t0 * ROW + h * 64 + lane;
            int tb = w * 64;
            #pragma unroll 4
            for (int i = 0; i < 64; ++i) {
                int t = tb + i;
                if (t < nloc) acc += sc[t] * vb[(long)t * ROW];
            }
        }
        red[w][lane] = acc;
        __syncthreads();

        if (w == 0) {
            float tot = 0.f;
            #pragma unroll
            for (int i = 0; i < 8; ++i) tot += red[i][lane];
            local_out[h * 64 + lane] = (nloc > 0) ? tot / S : 0.f;
        }
    }
}

// ---------------- K3: trivial combine: out = local + mean(node_out)
__global__ __launch_bounds__(256) void k3_combine(const float* __restrict__ node_out,
                                                  const float* __restrict__ local_out,
                                                  int nNodes,
                                                  float* __restrict__ out) {
    int i = blockIdx.x * 256 + threadIdx.x;    // 0..1023 = h*64+d
    float tr = 0.f;
    for (int n = 0; n < nNodes; ++n) tr += node_out[(long)n * ROW + i];
    if (nNodes > 0) tr /= (float)nNodes;
    out[i] = local_out[i] + tr;
}

static int floor_log2_host(unsigned x) { int r = 0; while (x >>= 1) ++r; return r; }

extern "C" void kernel_launch(void* const* d_in, const int* in_sizes, int n_in,
                              void* d_out, int out_size, void* d_ws, size_t ws_size,
                              hipStream_t stream) {
    const float* v    = (const float*)d_in[0];
    const float* q    = (const float*)d_in[1];
    const float* W    = (const float*)d_in[2];
    const float* temp = (const float*)d_in[3];
    float* out        = (float*)d_out;
    float* ws         = (float*)d_ws;

    int pos = in_sizes[0] / ROW;

    int n_nodes = 0;
    int nv[MAXN], nd[MAXN];
    if (pos > 0) {
        long l = LEAF_START;
        long r = LEAF_START + (pos < MAX_LEN_TOK ? pos : MAX_LEN_TOK);
        while (l < r) {
            if (l & 1) { nv[n_nodes] = (int)l; nd[n_nodes] = LOG_N - floor_log2_host((unsigned)l); ++n_nodes; ++l; }
            if (r & 1) { --r; nv[n_nodes] = (int)r; nd[n_nodes] = LOG_N - floor_log2_host((unsigned)r); ++n_nodes; }
            l >>= 1; r >>= 1;
        }
    }

    // cpb: smallest in {32,...} whose partial slices fit ws.
    // ws layout: partials | node_out [n_nodes*ROW] | local_out [ROW]
    int cpb_choice = 1024;
    for (int cand : {32, 64, 128, 256, 512, 1024}) {
        long tot_cb = 0;
        for (int i = 0; i < n_nodes; ++i) {
            int L = 1 << nd[i];
            int C = (L > KMAXN) ? L / KMAXN : 1;
            if (C > 1) tot_cb += (C + cand - 1) / cand;
        }
        long need = (tot_cb * (long)SLICE + (long)n_nodes * ROW + ROW) * 4;
        if (need <= (long)ws_size) { cpb_choice = cand; break; }
    }

    K1Args A1{}; K2Args A2{};
    A2.nNodes = n_nodes;
    int off = 0, bb = 0, nBig = 0;
    for (int i = 0; i < n_nodes; ++i) {
        int depth = nd[i];
        int L = 1 << depth;
        int a = (nv[i] << depth) - LEAF_START;
        int K = (L < KMAXN) ? L : KMAXN;
        int C = (L > KMAXN) ? L / KMAXN : 1;
        A2.K[i] = K; A2.C[i] = C; A2.a[i] = a; A2.depth[i] = depth;
        if (C > 1) {
            int CB  = (C + cpb_choice - 1) / cpb_choice;
            int cpb = (C + CB - 1) / CB;
            A1.a[nBig] = a; A1.cpb[nBig] = cpb; A1.C[nBig] = C;
            A1.CB[nBig] = CB;
            A1.off[nBig] = off; A1.bbase[nBig] = bb;
            A2.CB[i] = CB; A2.off[i] = off;
            off += CB * SLICE;
            bb  += 32 * CB;            // 2 k-rows per block (32 kg), cb-major
            ++nBig;
        } else {
            A2.CB[i] = 1; A2.off[i] = 0;
        }
    }
    A1.nNodes = nBig;

    float* node_outp  = ws + (long)off;                    // n_nodes * SLICE? no: n_nodes * ROW
    float* local_outp = node_outp + (long)n_nodes * ROW;   // ROW

    if (nBig > 0)
        hipLaunchKernelGGL(k1_reduce, dim3(bb), dim3(256), 0, stream, v, ws, A1);
    hipLaunchKernelGGL(k2_fused, dim3(NUM_HEADS, n_nodes + 1), dim3(512), 0, stream,
                       v, ws, q, W, temp, node_outp, local_outp, pos, A2);
    hipLaunchKernelGGL(k3_combine, dim3(4), dim3(256), 0, stream,
                       node_outp, local_outp, n_nodes, out);
}